// Round 3
// baseline (113.830 us; speedup 1.0000x reference)
//
#include <hip/hip_runtime.h>
#include <math.h>

constexpr int NPTS  = 16384;        // P == G
constexpr int BLOCK = 256;
constexpr int T     = 16;           // A-points per thread (register tile)
constexpr int ABLK  = BLOCK * T;    // 4096 A-points per block
constexpr int XBLK  = NPTS / ABLK;  // 4 blocks along A
constexpr int SPLIT = 128;          // B splits
constexpr int CHUNK = NPTS / SPLIT; // 128 B-points = 2 KB LDS

// ---------------------------------------------------------------------------
// Pack both clouds twice:
//   A-role: (x, y, z, ||r||^2)           — plain coords for the register tile
//   B-role: (-2x, -2y, -2z, ||r||^2)     — so per pair d = fma chain of 3
// Init min arrays to +inf bits; zero accum[4] + ticket. Runs every call
// (ws re-poisoned to 0xAA before each timed launch).
// ---------------------------------------------------------------------------
__global__ __launch_bounds__(BLOCK) void pack_init_kernel(
    const float* __restrict__ pred, const float* __restrict__ gt,
    float4* __restrict__ aP, float4* __restrict__ bP,
    float4* __restrict__ aG, float4* __restrict__ bG,
    unsigned int* __restrict__ minP, unsigned int* __restrict__ minG,
    float* __restrict__ accum, unsigned int* __restrict__ ticket)
{
    int i = blockIdx.x * BLOCK + threadIdx.x;
    if (i < NPTS) {
        float x = pred[3*i], y = pred[3*i+1], z = pred[3*i+2];
        float r2 = fmaf(x, x, fmaf(y, y, z*z));
        aP[i] = make_float4(x, y, z, r2);
        bP[i] = make_float4(-2.0f*x, -2.0f*y, -2.0f*z, r2);
        x = gt[3*i]; y = gt[3*i+1]; z = gt[3*i+2];
        r2 = fmaf(x, x, fmaf(y, y, z*z));
        aG[i] = make_float4(x, y, z, r2);
        bG[i] = make_float4(-2.0f*x, -2.0f*y, -2.0f*z, r2);
        minP[i] = 0x7F800000u;   // +inf
        minG[i] = 0x7F800000u;
    }
    if (i < 4) accum[i] = 0.0f;
    if (i == 4) *ticket = 0u;
}

// ---------------------------------------------------------------------------
// Fused both-direction min-distance. blockIdx.z picks direction.
// Per pair: t = fma(bx', ax, fma(by', ay, fma(bz', az, b2))) == b2 - 2 a.b
// 4 B-points per step; min tree shaped so the backend folds to v_min3_f32:
//   12 FMA + 3 min per 4 pairs = 3.75 VALU inst/pair.
// ---------------------------------------------------------------------------
__global__ __launch_bounds__(BLOCK, 4) void min_dist_kernel(
    const float4* __restrict__ aP, const float4* __restrict__ bP,
    const float4* __restrict__ aG, const float4* __restrict__ bG,
    unsigned int* __restrict__ minP, unsigned int* __restrict__ minG)
{
    const float4* __restrict__ A;
    const float4* __restrict__ B;
    unsigned int* __restrict__ out;
    if (blockIdx.z == 0) { A = aP; B = bG; out = minP; }
    else                 { A = aG; B = bP; out = minG; }

    __shared__ float4 sB[CHUNK];

    const int t     = threadIdx.x;
    const int aBase = blockIdx.x * ABLK;
    const int b0    = blockIdx.y * CHUNK;

    // Stage B chunk (128 float4 = 2 KB), first 128 threads.
    if (t < CHUNK) sB[t] = B[b0 + t];

    // Register tile: 16 A-points per thread, coalesced (stride BLOCK).
    float ax[T], ay[T], az[T], a2[T];
    #pragma unroll
    for (int k = 0; k < T; ++k) {
        float4 m = A[aBase + k * BLOCK + t];
        ax[k] = m.x; ay[k] = m.y; az[k] = m.z; a2[k] = m.w;
    }
    __syncthreads();

    float mn[T];
    #pragma unroll
    for (int k = 0; k < T; ++k) mn[k] = INFINITY;

    for (int j = 0; j < CHUNK; j += 4) {
        float4 u0 = sB[j+0];
        float4 u1 = sB[j+1];
        float4 u2 = sB[j+2];
        float4 u3 = sB[j+3];
        #pragma unroll
        for (int k = 0; k < T; ++k) {
            float t0 = fmaf(u0.x, ax[k], fmaf(u0.y, ay[k], fmaf(u0.z, az[k], u0.w)));
            float t1 = fmaf(u1.x, ax[k], fmaf(u1.y, ay[k], fmaf(u1.z, az[k], u1.w)));
            float t2 = fmaf(u2.x, ax[k], fmaf(u2.y, ay[k], fmaf(u2.z, az[k], u2.w)));
            float t3 = fmaf(u3.x, ax[k], fmaf(u3.y, ay[k], fmaf(u3.z, az[k], u3.w)));
            float p01 = fminf(t0, t1);
            float p23 = fminf(t2, t3);
            mn[k] = fminf(mn[k], fminf(p01, p23));   // -> v_min3_f32
        }
    }

    #pragma unroll
    for (int k = 0; k < T; ++k) {
        float d = fmaxf(a2[k] + mn[k], 0.0f);        // clamp commutes with min
        atomicMin(&out[aBase + k * BLOCK + t], __float_as_uint(d));
    }
}

// ---------------------------------------------------------------------------
// Fused weighted sums + finalize. blockIdx.y picks direction. Block-reduce,
// two atomicAdds per block, then a device-scope ticket: the last block to
// finish re-reads the accumulators (atomic RMW = coherent across XCDs) and
// writes the final scalar.
// ---------------------------------------------------------------------------
__global__ __launch_bounds__(BLOCK) void wsum_finalize_kernel(
    const unsigned int* __restrict__ minP,
    const unsigned int* __restrict__ minG,
    const float* __restrict__ wpred,
    const float* __restrict__ wgt,
    float* __restrict__ accum, unsigned int* __restrict__ ticket,
    float* __restrict__ outp)
{
    const unsigned int* mb = (blockIdx.y == 0) ? minP : minG;
    const float*        w  = (blockIdx.y == 0) ? wpred : wgt;
    float* acc = accum + 2 * blockIdx.y;

    int i = blockIdx.x * BLOCK + threadIdx.x;
    float num = 0.0f, den = 0.0f;
    if (i < NPTS) {
        float mv = __uint_as_float(mb[i]);
        float wv = w[i];
        num = wv * mv;
        den = wv;
    }
    for (int off = 32; off > 0; off >>= 1) {
        num += __shfl_down(num, off);
        den += __shfl_down(den, off);
    }
    __shared__ float snum[BLOCK/64], sden[BLOCK/64];
    int wid = threadIdx.x >> 6, lane = threadIdx.x & 63;
    if (lane == 0) { snum[wid] = num; sden[wid] = den; }
    __syncthreads();

    if (threadIdx.x == 0) {
        float tn = 0.0f, td = 0.0f;
        #pragma unroll
        for (int k = 0; k < BLOCK/64; ++k) { tn += snum[k]; td += sden[k]; }
        atomicAdd(&acc[0], tn);
        atomicAdd(&acc[1], td);
        __threadfence();                       // release accum before ticket
        unsigned int my = atomicAdd(ticket, 1u);
        const unsigned int NBLK = (NPTS / BLOCK) * 2;
        if (my == NBLK - 1) {                  // last block finalizes
            __threadfence();
            float n0 = atomicAdd(&accum[0], 0.0f);  // atomic RMW reads:
            float d0 = atomicAdd(&accum[1], 0.0f);  // coherent across XCDs
            float n1 = atomicAdd(&accum[2], 0.0f);
            float d1 = atomicAdd(&accum[3], 0.0f);
            outp[0] = n0 / fmaxf(d0, 1e-9f) + n1 / fmaxf(d1, 1e-9f);
        }
    }
}

// ---------------------------------------------------------------------------
extern "C" void kernel_launch(void* const* d_in, const int* in_sizes, int n_in,
                              void* d_out, int out_size, void* d_ws, size_t ws_size,
                              hipStream_t stream)
{
    const float* pred  = (const float*)d_in[0];   // (P,3)
    const float* gt    = (const float*)d_in[1];   // (G,3)
    const float* wpred = (const float*)d_in[2];   // (P,)
    const float* wgt   = (const float*)d_in[3];   // (G,)
    float* out = (float*)d_out;

    // ws layout: aP | bP | aG | bG | minP | minG | accum[4] | ticket  (~1.2 MB)
    float4* aP = (float4*)d_ws;
    float4* bP = aP + NPTS;
    float4* aG = bP + NPTS;
    float4* bG = aG + NPTS;
    unsigned int* minP = (unsigned int*)(bG + NPTS);
    unsigned int* minG = minP + NPTS;
    float* accum = (float*)(minG + NPTS);
    unsigned int* ticket = (unsigned int*)(accum + 4);

    pack_init_kernel<<<NPTS / BLOCK, BLOCK, 0, stream>>>(
        pred, gt, aP, bP, aG, bG, minP, minG, accum, ticket);

    dim3 grid(XBLK, SPLIT, 2);   // 4 x 128 x 2 = 1024 blocks
    min_dist_kernel<<<grid, BLOCK, 0, stream>>>(aP, bP, aG, bG, minP, minG);

    wsum_finalize_kernel<<<dim3(NPTS / BLOCK, 2), BLOCK, 0, stream>>>(
        minP, minG, wpred, wgt, accum, ticket, out);
}